// Round 5
// baseline (87.617 us; speedup 1.0000x reference)
//
#include <hip/hip_runtime.h>

#define NEXP 8
#define NBLK 256
#define NTHR 1024

typedef unsigned long long u64;
typedef unsigned int u32;

// one 33 KB LDS arena shared across the three phases
union __align__(16) Smem {
    struct { float wl[NEXP * 1024]; double zred[16]; } a;   // phase A
    struct { u64 keys[2048]; int part[NTHR]; } b;           // phase B
    struct { int avail[2048]; int cnt[32]; int cnt2[32]; } c; // phase C
};

__global__ __launch_bounds__(NTHR, 4) void moe_router_kernel(
    const float* __restrict__ x,      // [GT, 1024]
    const float* __restrict__ w,      // [8, 1024]
    const float* __restrict__ bias,   // [8]
    float* __restrict__ out,
    float* __restrict__ probsT,       // [E][GT]
    u64* __restrict__ skey,           // [E*G][T]
    double* __restrict__ zpart,       // [NBLK]
    int* __restrict__ bar,            // [2] zeroed per call
    long long nout4, long long GT, int T, int G, int cap)
{
    __shared__ Smem sm;
    const int b = blockIdx.x;
    const int tid = threadIdx.x;
    const int lane = tid & 63;
    const int wv = tid >> 6;

    // ================= phase A: stage W, zero-fill, probs =================
    for (int i = tid; i < NEXP * 1024 / 4; i += NTHR)
        reinterpret_cast<float4*>(sm.a.wl)[i] = reinterpret_cast<const float4*>(w)[i];
    __syncthreads();

    {   // zero-fill d_out (stores drain async under the probs compute)
        const float4 z = make_float4(0.f, 0.f, 0.f, 0.f);
        for (long long k = (long long)b * NTHR + tid; k < nout4; k += (long long)NBLK * NTHR)
            reinterpret_cast<float4*>(out)[k] = z;
    }

    {   // probs: 32 tokens per block, 2 per wave (f64 softmax, bit-identical)
        double zacc = 0.0;
#pragma unroll
        for (int s = 0; s < 2; ++s) {
            const long long t = (long long)b * 32 + wv * 2 + s;
            const float* xr = x + t * 1024;
            float acc[NEXP];
#pragma unroll
            for (int e = 0; e < NEXP; ++e) acc[e] = 0.f;
#pragma unroll
            for (int c = 0; c < 4; ++c) {
                const float4 xv = reinterpret_cast<const float4*>(xr)[c * 64 + lane];
#pragma unroll
                for (int e = 0; e < NEXP; ++e) {
                    const float4 wv4 = reinterpret_cast<const float4*>(sm.a.wl + e * 1024)[c * 64 + lane];
                    acc[e] = fmaf(xv.x, wv4.x, acc[e]);
                    acc[e] = fmaf(xv.y, wv4.y, acc[e]);
                    acc[e] = fmaf(xv.z, wv4.z, acc[e]);
                    acc[e] = fmaf(xv.w, wv4.w, acc[e]);
                }
            }
#pragma unroll
            for (int e = 0; e < NEXP; ++e) {
#pragma unroll
                for (int off = 32; off; off >>= 1) acc[e] += __shfl_xor(acc[e], off, 64);
            }
            if (lane == 0) {
                double l[NEXP]; double mx = -1e300;
#pragma unroll
                for (int e = 0; e < NEXP; ++e) { l[e] = (double)acc[e] + (double)bias[e]; mx = fmax(mx, l[e]); }
                double ex[NEXP]; double ssum = 0.0;
#pragma unroll
                for (int e = 0; e < NEXP; ++e) { ex[e] = exp(l[e] - mx); ssum += ex[e]; }
                const double inv = 1.0 / ssum;
#pragma unroll
                for (int e = 0; e < NEXP; ++e) probsT[(long long)e * GT + t] = (float)(ex[e] * inv);
                const double lse = mx + log(ssum);
                zacc += lse * lse;
            }
        }
        if (lane == 0) sm.a.zred[wv] = zacc;
    }
    __syncthreads();
    if (tid == 0) {
        double s = 0.0;
#pragma unroll
        for (int i = 0; i < 16; ++i) s += sm.a.zred[i];
        zpart[b] = s;
    }

    // ================= grid barrier 1 (all wait) =================
    __syncthreads();
    if (tid == 0) {
        __threadfence();
        atomicAdd(&bar[0], 1);
        while (__hip_atomic_load(&bar[0], __ATOMIC_RELAXED, __HIP_MEMORY_SCOPE_AGENT) < NBLK)
            __builtin_amdgcn_s_sleep(2);
        __threadfence();
    }
    __syncthreads();

    // ================= phase B: ranksort (4 threads per token) =================
    {
        const int pair = b >> 3;            // = e*G + g
        const int sub  = b & 7;             // token slice [sub*256, +256)
        const int e = pair / G;
        const int g = pair - e * G;
        const float* p = probsT + (long long)e * GT + (long long)g * T;
        for (int j = tid; j < 2048; j += NTHR)
            sm.b.keys[j] = ((u64)__float_as_uint(p[j]) << 32) | (u32)(~(u32)j);
        __syncthreads();
        const int slot = tid & 255;
        const int q = tid >> 8;             // key-range quarter 0..3
        const u64 kt = sm.b.keys[sub * 256 + slot];
        const ulonglong2* k2 = reinterpret_cast<const ulonglong2*>(sm.b.keys) + q * 256;
        int r = 0;
#pragma unroll 8
        for (int j = 0; j < 256; ++j) {
            const ulonglong2 v = k2[j];
            r += (v.x > kt); r += (v.y > kt);
        }
        sm.b.part[tid] = r;
        __syncthreads();
        if (tid < 256) {
            const int rank = sm.b.part[tid] + sm.b.part[tid + 256] + sm.b.part[tid + 512] + sm.b.part[tid + 768];
            skey[(long long)pair * T + rank] = sm.b.keys[sub * 256 + tid];
        }
    }

    // ================= grid barrier 2 (blocks >= G arrive & exit) =================
    __syncthreads();
    if (b >= G) {
        if (tid == 0) { __threadfence(); atomicAdd(&bar[1], 1); }
        return;
    }
    if (tid == 0) {
        __threadfence();
        atomicAdd(&bar[1], 1);
        while (__hip_atomic_load(&bar[1], __ATOMIC_RELAXED, __HIP_MEMORY_SCOPE_AGENT) < NBLK)
            __builtin_amdgcn_s_sleep(2);
        __threadfence();
    }
    __syncthreads();

    // ================= phase C: assign (blocks 0..G-1) =================
    const int g = b;
    u64 ka[NEXP], kb[NEXP];                 // prefetch all experts' keys
#pragma unroll
    for (int e = 0; e < NEXP; ++e) {
        const long long base = (long long)(e * G + g) * T;
        ka[e] = skey[base + tid];
        kb[e] = skey[base + tid + 1024];
    }
    sm.c.avail[tid] = 1;
    sm.c.avail[tid + 1024] = 1;

    float* dispatch = out;
    float* combine  = out + GT * (long long)NEXP * cap;
    const long long gbase = (long long)g * T;
    const u64 lmask = (lane == 0) ? 0ull : ((~0ull) >> (64 - lane));

    for (int e = 0; e < NEXP; ++e) {
        __syncthreads();                    // B_top: prev updates / init visible
        const u64 k0 = ka[e], k1 = kb[e];
        const u32 idx0 = ~(u32)k0, idx1 = ~(u32)k1;
        const float v0 = __uint_as_float((u32)(k0 >> 32));
        const float v1 = __uint_as_float((u32)(k1 >> 32));
        const int f0 = sm.c.avail[idx0];
        const int f1 = sm.c.avail[idx1];
        const u64 m0 = __ballot(f0);
        const u64 m1 = __ballot(f1);
        if (lane == 0) { sm.c.cnt[wv] = __popcll(m0); sm.c.cnt[16 + wv] = __popcll(m1); }
        __syncthreads();                    // B1
        // every wave redundantly scans cnt[0..31] (no broadcast barrier needed)
        int vi = (lane < 32) ? sm.c.cnt[lane] : 0;
#pragma unroll
        for (int o = 1; o < 32; o <<= 1) { const int t2 = __shfl_up(vi, o, 64); if (lane >= o) vi += t2; }
        const int off0 = wv ? __shfl(vi, wv - 1, 64) : 0;   // exclusive prefix of segment wv
        const int off1 = __shfl(vi, 15 + wv, 64);           // exclusive prefix of segment 16+wv
        const int S    = __shfl(vi, 31, 64);
        const int pre0 = off0 + __popcll(m0 & lmask);
        const int pre1 = off1 + __popcll(m1 & lmask);
        const bool s0 = f0 && (pre0 < cap);
        const bool s1 = f1 && (pre1 < cap);
        if (s0) { const long long o_ = ((gbase + idx0) * NEXP + e) * (long long)cap + pre0; dispatch[o_] = 1.0f; combine[o_] = v0; }
        if (s1) { const long long o_ = ((gbase + idx1) * NEXP + e) * (long long)cap + pre1; dispatch[o_] = 1.0f; combine[o_] = v1; }
        if (S < cap) {
            // zero-gate fill: smallest-index unavailable tokens (combine stays 0)
            const int u0 = 1 - sm.c.avail[tid];
            const int u1 = 1 - sm.c.avail[tid + 1024];
            const u64 n0 = __ballot(u0);
            const u64 n1 = __ballot(u1);
            if (lane == 0) { sm.c.cnt2[wv] = __popcll(n0); sm.c.cnt2[16 + wv] = __popcll(n1); }
            __syncthreads();                // B2: cnt2 visible; also orders u-reads before updates
            int vj = (lane < 32) ? sm.c.cnt2[lane] : 0;
#pragma unroll
            for (int o = 1; o < 32; o <<= 1) { const int t2 = __shfl_up(vj, o, 64); if (lane >= o) vj += t2; }
            const int qoff0 = wv ? __shfl(vj, wv - 1, 64) : 0;
            const int qoff1 = __shfl(vj, 15 + wv, 64);
            const int q0 = qoff0 + __popcll(n0 & lmask);
            const int q1 = qoff1 + __popcll(n1 & lmask);
            const int nfill = cap - S;
            if (u0 && q0 < nfill) { const long long o_ = ((gbase + tid) * NEXP + e) * (long long)cap + S + q0; dispatch[o_] = 1.0f; }
            if (u1 && q1 < nfill) { const long long o_ = ((gbase + tid + 1024) * NEXP + e) * (long long)cap + S + q1; dispatch[o_] = 1.0f; }
        }
        if (s0) sm.c.avail[idx0] = 0;       // updates: after B1 (f-reads) / B2 (u-reads)
        if (s1) sm.c.avail[idx1] = 0;
    }

    // z_loss scalars
    if (g == 0 && tid < 64) {
        double s = zpart[tid] + zpart[tid + 64] + zpart[tid + 128] + zpart[tid + 192];
#pragma unroll
        for (int o = 32; o; o >>= 1) s += __shfl_xor(s, o, 64);
        if (tid == 0) {
            float* sc = out + 2 * GT * (long long)NEXP * cap;
            sc[0] = 0.0f;
            sc[1] = (float)(s / (double)GT);
            sc[2] = 0.0f;
        }
    }
}

extern "C" void kernel_launch(void* const* d_in, const int* in_sizes, int n_in,
                              void* d_out, int out_size, void* d_ws, size_t ws_size,
                              hipStream_t stream) {
    (void)n_in; (void)ws_size;
    const float* x    = (const float*)d_in[0];
    const float* w    = (const float*)d_in[1];
    const float* bias = (const float*)d_in[2];

    const int E = in_sizes[2];                        // 8
    const int D = in_sizes[1] / E;                    // 1024
    const long long GT = (long long)in_sizes[0] / D;  // 8192
    const int T = 2048;
    const int G = (int)(GT / T);                      // 4
    const int cap = (int)(((long long)out_size - 3) / (2 * GT * E));
    const long long nout4 = ((long long)out_size - 3) >> 2;

    int*    bar    = (int*)d_ws;                                   // [0,16)
    double* zpart  = (double*)((char*)d_ws + 4096);                // 2 KB
    float*  probsT = (float*)((char*)d_ws + 16384);                // E*GT*4
    u64*    skey   = (u64*)((char*)d_ws + 16384 + (size_t)E * GT * sizeof(float));

    hipMemsetAsync(bar, 0, 16, stream);   // barrier counters must be 0 each call

    moe_router_kernel<<<NBLK, NTHR, 0, stream>>>(
        x, w, bias, (float*)d_out, probsT, skey, zpart, bar,
        nout4, GT, T, G, cap);
}

// Round 6
// 71.155 us; speedup vs baseline: 1.2314x; 1.2314x over previous
//
#include <hip/hip_runtime.h>

#define NEXP 8
typedef unsigned long long u64;
typedef unsigned int u32;

// ---------------- kernel 1: fused probs (blocks [0,npb)) + zero-fill ----------
__global__ __launch_bounds__(512) void probs_fill_kernel(
    const float* __restrict__ x,      // [GT, 1024]
    const float* __restrict__ w,      // [8, 1024]
    const float* __restrict__ bias,   // [8]
    float* __restrict__ probsT,       // [E][GT]
    double* __restrict__ zpart,       // [npb]
    int* __restrict__ flags,          // [8] -> zeroed here for kernel 2
    float* __restrict__ out,
    long long nout4,                  // float4 count of d_out (excl. 3-scalar tail)
    long long GT, int npb, int nfb)
{
    if (blockIdx.x == 0 && threadIdx.x < 8) flags[threadIdx.x] = 0;

    if ((int)blockIdx.x >= npb) {
        // ---- zero-fill path: no LDS, no barriers ----
        const int fb = (int)blockIdx.x - npb;
        const long long stride = (long long)nfb * 512;
        const float4 z = make_float4(0.f, 0.f, 0.f, 0.f);
        for (long long k = (long long)fb * 512 + threadIdx.x; k < nout4; k += stride) {
            reinterpret_cast<float4*>(out)[k] = z;
        }
        return;
    }

    // ---- probs path ----
    __shared__ float wl[NEXP * 1024];
    __shared__ double zred[8];
    for (int i = threadIdx.x; i < NEXP * 1024 / 4; i += 512) {
        reinterpret_cast<float4*>(wl)[i] = reinterpret_cast<const float4*>(w)[i];
    }
    __syncthreads();

    const int wave = threadIdx.x >> 6;
    const int lane = threadIdx.x & 63;
    const long long t = (long long)blockIdx.x * 8 + wave;
    const float* xr = x + t * 1024;

    float acc[NEXP];
#pragma unroll
    for (int e = 0; e < NEXP; ++e) acc[e] = 0.f;

#pragma unroll
    for (int c = 0; c < 4; ++c) {
        const int d = c * 256 + lane * 4;
        const float4 xv = *reinterpret_cast<const float4*>(xr + d);
#pragma unroll
        for (int e = 0; e < NEXP; ++e) {
            const float4 wv = *reinterpret_cast<const float4*>(wl + e * 1024 + d);
            acc[e] = fmaf(xv.x, wv.x, acc[e]);
            acc[e] = fmaf(xv.y, wv.y, acc[e]);
            acc[e] = fmaf(xv.z, wv.z, acc[e]);
            acc[e] = fmaf(xv.w, wv.w, acc[e]);
        }
    }
#pragma unroll
    for (int e = 0; e < NEXP; ++e) {
#pragma unroll
        for (int off = 32; off; off >>= 1) acc[e] += __shfl_xor(acc[e], off, 64);
    }

    if (lane == 0) {
        double l[NEXP];
        double mx = -1e300;
#pragma unroll
        for (int e = 0; e < NEXP; ++e) {
            l[e] = (double)acc[e] + (double)bias[e];
            mx = fmax(mx, l[e]);
        }
        double ex[NEXP];
        double s = 0.0;
#pragma unroll
        for (int e = 0; e < NEXP; ++e) { ex[e] = exp(l[e] - mx); s += ex[e]; }
        const double inv = 1.0 / s;
#pragma unroll
        for (int e = 0; e < NEXP; ++e) probsT[(long long)e * GT + t] = (float)(ex[e] * inv);
        const double lse = mx + log(s);
        zred[wave] = lse * lse;
    }
    __syncthreads();
    if (threadIdx.x == 0) {
        double s = 0.0;
#pragma unroll
        for (int i = 0; i < 8; ++i) s += zred[i];
        zpart[blockIdx.x] = s;
    }
}

// ---------------- kernel 2: ranksort (blocks 0..255) + assign (blocks 256..259) --
#define NRANK 256

union __align__(16) Smem2 {
    struct { u64 keys[2048]; int part[1024]; } b;            // rank path (20 KB)
    struct { int avail[2048]; int cnt[32]; int cnt2[32]; } c; // assign path
};

__global__ __launch_bounds__(1024) void rank_assign_kernel(
    const float* __restrict__ probsT,  // [E][GT]
    u64* __restrict__ skey,            // [E*G][T]
    int* __restrict__ flags,           // [8], zeroed by kernel 1
    const double* __restrict__ zpart,
    int nzpart,
    float* __restrict__ out,
    int T, int G, int cap, long long GT)
{
    __shared__ Smem2 sm;
    const int b = blockIdx.x;
    const int tid = threadIdx.x;
    const int lane = tid & 63;
    const int wv = tid >> 6;

    if (b < NRANK) {
        // ---- ranksort slice: pair = e*G+g, 1/8 of its 2048 tokens ----
        const int pair = b >> 3;
        const int sub  = b & 7;
        const int e = pair / G;
        const int g = pair - e * G;
        const float* p = probsT + (long long)e * GT + (long long)g * T;
        for (int j = tid; j < 2048; j += 1024)
            sm.b.keys[j] = ((u64)__float_as_uint(p[j]) << 32) | (u32)(~(u32)j);
        __syncthreads();
        const int slot = tid & 255;
        const int q = tid >> 8;            // compare-range quarter 0..3
        const u64 kt = sm.b.keys[sub * 256 + slot];
        const ulonglong2* k2 = reinterpret_cast<const ulonglong2*>(sm.b.keys) + q * 256;
        int r = 0;
#pragma unroll 8
        for (int j = 0; j < 256; ++j) {
            const ulonglong2 v = k2[j];
            r += (v.x > kt); r += (v.y > kt);
        }
        sm.b.part[tid] = r;
        __syncthreads();
        if (tid < 256) {
            const int rank = sm.b.part[tid] + sm.b.part[tid + 256] + sm.b.part[tid + 512] + sm.b.part[tid + 768];
            skey[(long long)pair * T + rank] = sm.b.keys[sub * 256 + tid];
        }
        __syncthreads();
        if (tid == 0) { __threadfence(); atomicAdd(&flags[g], 1); }
        return;
    }

    // ---- assign block for group g: wait for its 64 producer blocks ----
    const int g = b - NRANK;
    if (tid == 0) {
        while (__hip_atomic_load(&flags[g], __ATOMIC_RELAXED, __HIP_MEMORY_SCOPE_AGENT) < 64)
            __builtin_amdgcn_s_sleep(2);
        __threadfence();   // acquire: skey writes visible
    }
    __syncthreads();

    u64 ka[NEXP], kb[NEXP];               // prefetch all experts' keys
#pragma unroll
    for (int e = 0; e < NEXP; ++e) {
        const long long base = (long long)(e * G + g) * T;
        ka[e] = skey[base + tid];
        kb[e] = skey[base + tid + 1024];
    }
    sm.c.avail[tid] = 1;
    sm.c.avail[tid + 1024] = 1;

    float* dispatch = out;
    float* combine  = out + GT * (long long)NEXP * cap;
    const long long gbase = (long long)g * T;
    const u64 lmask = (lane == 0) ? 0ull : ((~0ull) >> (64 - lane));

    for (int e = 0; e < NEXP; ++e) {
        __syncthreads();                  // B_top: prev updates / init visible
        const u64 k0 = ka[e], k1 = kb[e];
        const u32 idx0 = ~(u32)k0, idx1 = ~(u32)k1;
        const float v0 = __uint_as_float((u32)(k0 >> 32));
        const float v1 = __uint_as_float((u32)(k1 >> 32));
        const int f0 = sm.c.avail[idx0];
        const int f1 = sm.c.avail[idx1];
        const u64 m0 = __ballot(f0);
        const u64 m1 = __ballot(f1);
        if (lane == 0) { sm.c.cnt[wv] = __popcll(m0); sm.c.cnt[16 + wv] = __popcll(m1); }
        __syncthreads();                  // B1
        // every wave redundantly scans cnt[0..31]
        int vi = (lane < 32) ? sm.c.cnt[lane] : 0;
#pragma unroll
        for (int o = 1; o < 32; o <<= 1) { const int t2 = __shfl_up(vi, o, 64); if (lane >= o) vi += t2; }
        const int off0 = wv ? __shfl(vi, wv - 1, 64) : 0;
        const int off1 = __shfl(vi, 15 + wv, 64);
        const int S    = __shfl(vi, 31, 64);
        const int pre0 = off0 + __popcll(m0 & lmask);
        const int pre1 = off1 + __popcll(m1 & lmask);
        const bool s0 = f0 && (pre0 < cap);
        const bool s1 = f1 && (pre1 < cap);
        if (s0) { const long long o_ = ((gbase + idx0) * NEXP + e) * (long long)cap + pre0; dispatch[o_] = 1.0f; combine[o_] = v0; }
        if (s1) { const long long o_ = ((gbase + idx1) * NEXP + e) * (long long)cap + pre1; dispatch[o_] = 1.0f; combine[o_] = v1; }
        if (S < cap) {
            // zero-gate fill: smallest-index unavailable tokens (combine stays 0)
            const int u0 = 1 - sm.c.avail[tid];
            const int u1 = 1 - sm.c.avail[tid + 1024];
            const u64 n0 = __ballot(u0);
            const u64 n1 = __ballot(u1);
            if (lane == 0) { sm.c.cnt2[wv] = __popcll(n0); sm.c.cnt2[16 + wv] = __popcll(n1); }
            __syncthreads();              // B2: cnt2 visible; orders u-reads before updates
            int vj = (lane < 32) ? sm.c.cnt2[lane] : 0;
#pragma unroll
            for (int o = 1; o < 32; o <<= 1) { const int t2 = __shfl_up(vj, o, 64); if (lane >= o) vj += t2; }
            const int qoff0 = wv ? __shfl(vj, wv - 1, 64) : 0;
            const int qoff1 = __shfl(vj, 15 + wv, 64);
            const int q0 = qoff0 + __popcll(n0 & lmask);
            const int q1 = qoff1 + __popcll(n1 & lmask);
            const int nfill = cap - S;
            if (u0 && q0 < nfill) { const long long o_ = ((gbase + tid) * NEXP + e) * (long long)cap + S + q0; dispatch[o_] = 1.0f; }
            if (u1 && q1 < nfill) { const long long o_ = ((gbase + tid + 1024) * NEXP + e) * (long long)cap + S + q1; dispatch[o_] = 1.0f; }
        }
        if (s0) sm.c.avail[idx0] = 0;     // after B1 (f-reads) / B2 (u-reads)
        if (s1) sm.c.avail[idx1] = 0;
    }

    // z_loss scalars (group-0 assign block)
    if (g == 0 && tid < 64) {
        double s = 0.0;
        for (int i = tid; i < nzpart; i += 64) s += zpart[i];
#pragma unroll
        for (int o = 32; o; o >>= 1) s += __shfl_xor(s, o, 64);
        if (tid == 0) {
            float* sc = out + 2 * GT * (long long)NEXP * cap;
            sc[0] = 0.0f;
            sc[1] = (float)(s / (double)GT);
            sc[2] = 0.0f;
        }
    }
}

extern "C" void kernel_launch(void* const* d_in, const int* in_sizes, int n_in,
                              void* d_out, int out_size, void* d_ws, size_t ws_size,
                              hipStream_t stream) {
    (void)n_in; (void)ws_size;
    const float* x    = (const float*)d_in[0];
    const float* w    = (const float*)d_in[1];
    const float* bias = (const float*)d_in[2];

    const int E = in_sizes[2];                        // 8
    const int D = in_sizes[1] / E;                    // 1024
    const long long GT = (long long)in_sizes[0] / D;  // 8192
    const int T = 2048;
    const int G = (int)(GT / T);                      // 4
    const int cap = (int)(((long long)out_size - 3) / (2 * GT * E));
    const int npb = (int)(GT / 8);                    // 1024 probs blocks
    const int nfb = 2048;                             // fill blocks

    int*    flags  = (int*)d_ws;                                   // [0,32)
    double* zpart  = (double*)((char*)d_ws + 4096);                // npb*8 B
    float*  probsT = (float*)((char*)d_ws + 16384);                // E*GT*4
    u64*    skey   = (u64*)((char*)d_ws + 16384 + (size_t)E * GT * sizeof(float));

    const long long nout4 = ((long long)out_size - 3) >> 2;

    probs_fill_kernel<<<npb + nfb, 512, 0, stream>>>(
        x, w, bias, probsT, zpart, flags, (float*)d_out, nout4, GT, npb, nfb);

    rank_assign_kernel<<<NRANK + G, 1024, 0, stream>>>(
        probsT, skey, flags, zpart, npb, (float*)d_out, T, G, cap, GT);
}